// Round 2
// baseline (232345.215 us; speedup 1.0000x reference)
//
#include <hip/hip_runtime.h>
#include <hip/hip_bf16.h>

// ---------------- types ----------------
typedef _Float16 half2_t __attribute__((ext_vector_type(2)));
typedef _Float16 half8_t __attribute__((ext_vector_type(8)));
typedef float float4_t __attribute__((ext_vector_type(4)));

#define SEQ   8192
#define ISZ   512
#define HID   2048
#define G4H   8192   // 4*HID
#define NB    256    // persistent blocks (== CU count)

#if __has_builtin(__builtin_amdgcn_fdot2)
#define DOT2(a, b, c) __builtin_amdgcn_fdot2((a), (b), (c), false)
#else
static __device__ __forceinline__ float DOT2(half2_t a, half2_t b, float c) {
    return c + (float)a.x * (float)b.x + (float)a.y * (float)b.y;
}
#endif

// ---------------- f32 -> f16 convert ----------------
__global__ __launch_bounds__(256) void cvt_f32_f16(const float* __restrict__ in,
                                                   _Float16* __restrict__ out, int n) {
    int i = (blockIdx.x * 256 + threadIdx.x) * 4;
    if (i < n) {
        float4 v = *(const float4*)(in + i);
        out[i + 0] = (_Float16)v.x;
        out[i + 1] = (_Float16)v.y;
        out[i + 2] = (_Float16)v.z;
        out[i + 3] = (_Float16)v.w;
    }
}

// ---------------- init h buffer + epoch counters ----------------
// cnt[t*16] counts blocks that have published h_t. cnt[0] preset to NB (h_0 = 0).
__global__ __launch_bounds__(256) void init_state(_Float16* __restrict__ hbuf,
                                                  unsigned* __restrict__ cnt) {
    int i = blockIdx.x * 256 + threadIdx.x;
    if (i < 2 * HID) ((unsigned short*)hbuf)[i] = 0;  // both parity slots = 0
    if (i < (SEQ + 1) * 16) cnt[i] = (i == 0) ? (unsigned)NB : 0u;
}

// ---------------- x_proj GEMM: C[m][n] = sum_k A[m][k]*B[n][k] (f16 in, f16 out, f32 acc)
__global__ __launch_bounds__(256) void gemm_xproj(const _Float16* __restrict__ A,  // [SEQ][ISZ]
                                                  const _Float16* __restrict__ B,  // [G4H][ISZ]
                                                  _Float16* __restrict__ C) {      // [SEQ][G4H]
    __shared__ _Float16 As[128 * 40];
    __shared__ _Float16 Bs[128 * 40];
    const int tid = threadIdx.x;
    const int bm = blockIdx.y, bn = blockIdx.x;
    const int wave = tid >> 6, lane = tid & 63;
    const int wr = wave >> 1, wc = wave & 1;
    const int l15 = lane & 15, lq = lane >> 4;

    float4_t acc[4][4];
#pragma unroll
    for (int im = 0; im < 4; im++)
#pragma unroll
        for (int in = 0; in < 4; in++)
#pragma unroll
            for (int r = 0; r < 4; r++) acc[im][in][r] = 0.f;

    for (int kt = 0; kt < ISZ; kt += 32) {
        __syncthreads();
#pragma unroll
        for (int ld = 0; ld < 2; ld++) {
            int c = tid + ld * 256;
            int r = c >> 2, ko = (c & 3) * 8;
            uint4 av = *(const uint4*)(A + (size_t)(bm * 128 + r) * ISZ + kt + ko);
            *(uint4*)(As + r * 40 + ko) = av;
            uint4 bv = *(const uint4*)(B + (size_t)(bn * 128 + r) * ISZ + kt + ko);
            *(uint4*)(Bs + r * 40 + ko) = bv;
        }
        __syncthreads();
        half8_t af[4], bf[4];
#pragma unroll
        for (int im = 0; im < 4; im++)
            af[im] = *(half8_t*)(As + (wr * 64 + im * 16 + l15) * 40 + lq * 8);
#pragma unroll
        for (int in = 0; in < 4; in++)
            bf[in] = *(half8_t*)(Bs + (wc * 64 + in * 16 + l15) * 40 + lq * 8);
#pragma unroll
        for (int im = 0; im < 4; im++)
#pragma unroll
            for (int in = 0; in < 4; in++)
                acc[im][in] = __builtin_amdgcn_mfma_f32_16x16x32_f16(af[im], bf[in], acc[im][in], 0, 0, 0);
    }
#pragma unroll
    for (int im = 0; im < 4; im++) {
        int mg = bm * 128 + wr * 64 + im * 16 + lq * 4;
#pragma unroll
        for (int in = 0; in < 4; in++) {
            int ng = bn * 128 + wc * 64 + in * 16 + l15;
#pragma unroll
            for (int r = 0; r < 4; r++)
                C[(size_t)(mg + r) * G4H + ng] = (_Float16)acc[im][in][r];
        }
    }
}

// ---------------- persistent LSTM recurrence ----------------
// Block b owns h elements [b*8, b*8+8); wave g computes gate g for those rows.
// Weights in VGPRs (f16). Chip-wide step sync = 1 atomicAdd + 1-word poll.
__global__ __launch_bounds__(256, 1) void lstm_persist(
    const float* __restrict__ Whh,   // [G4H][HID] f32
    const float* __restrict__ b_ih, const float* __restrict__ b_hh,
    const _Float16* __restrict__ xp, // [SEQ][G4H] f16
    const float* __restrict__ fcw, const float* __restrict__ fcb,
    _Float16* __restrict__ hbuf,     // [2][HID] f16
    unsigned* __restrict__ cnt,      // [(SEQ+1)*16] u32, stride 16 (64 B lines)
    float* __restrict__ out) {
    const int b = blockIdx.x, tid = threadIdx.x;
    const int g = tid >> 6, lane = tid & 63;

    __shared__ float gate_lds[4][8];
    __shared__ unsigned short h16[8];
    __shared__ float red[4];

    // --- prologue: weight slice into registers (f32 -> f16) ---
    half2_t w[8][16];  // 8 rows x 32 cols -> 128 VGPRs
#pragma unroll
    for (int e = 0; e < 8; e++) {
        const float* wp = Whh + (size_t)(g * HID + b * 8 + e) * HID + lane * 32;
#pragma unroll
        for (int i = 0; i < 16; i++) {
            float2 f = *(const float2*)(wp + i * 2);
            half2_t h2;
            h2.x = (_Float16)f.x;
            h2.y = (_Float16)f.y;
            w[e][i] = h2;
        }
    }
    float bias_r = 0.f;
    if (lane < 8) {
        int R = g * HID + b * 8 + lane;
        bias_r = b_ih[R] + b_hh[R];
    }
    float c_reg = 0.f;  // cell state, held by tid<8

    for (int t = 0; t < SEQ; ++t) {
        // x_proj prefetch (independent of h)
        float xpv = 0.f;
        if (lane < 8)
            xpv = (float)xp[(size_t)t * G4H + g * HID + b * 8 + lane];

        // wait until all 256 blocks published h_t: single-word poll by one thread
        if (tid == 0) {
            while (__hip_atomic_load(&cnt[(size_t)t * 16], __ATOMIC_RELAXED,
                                     __HIP_MEMORY_SCOPE_AGENT) < (unsigned)NB) {
            }
        }
        __syncthreads();
        __threadfence();  // acquire: invalidate stale L1/L2 before reading h

        // load h slice [lane*32, lane*32+32) into registers
        const uint4* hp = (const uint4*)(hbuf + (size_t)(t & 1) * HID);
        union {
            uint4 u[4];
            half2_t h2[16];
        } hu;
#pragma unroll
        for (int i = 0; i < 4; i++) hu.u[i] = hp[lane * 4 + i];

        // matvec: 8 rows x 32 cols per thread
        float acc[8];
#pragma unroll
        for (int e = 0; e < 8; e++) {
            float a = 0.f;
#pragma unroll
            for (int i = 0; i < 16; i++) a = DOT2(w[e][i], hu.h2[i], a);
            acc[e] = a;
        }
        // full-wave butterfly reduce (all 8 rows)
#pragma unroll
        for (int off = 1; off < 64; off <<= 1)
#pragma unroll
            for (int e = 0; e < 8; e++) acc[e] += __shfl_xor(acc[e], off, 64);

        if (lane < 8) {
            float v = acc[0];
#pragma unroll
            for (int e = 1; e < 8; e++)
                if (lane == e) v = acc[e];
            gate_lds[g][lane] = v + bias_r + xpv;
        }
        __syncthreads();

        if (tid < 8) {
            float gi = gate_lds[0][tid], gf = gate_lds[1][tid];
            float gg = gate_lds[2][tid], go = gate_lds[3][tid];
            float si = 1.f / (1.f + __expf(-gi));
            float sf = 1.f / (1.f + __expf(-gf));
            float so = 1.f / (1.f + __expf(-go));
            float tg = tanhf(gg);
            c_reg = sf * c_reg + si * tg;
            float h = so * tanhf(c_reg);
            _Float16 hh = (_Float16)h;
            h16[tid] = *(unsigned short*)&hh;
        }
        __syncthreads();

        if (tid == 0) {
            uint4 hv = *(const uint4*)h16;
            *(uint4*)(hbuf + (size_t)((t + 1) & 1) * HID + b * 8) = hv;
            __threadfence();  // release: h visible in L3 before the count bump
            atomicAdd(&cnt[(size_t)(t + 1) * 16], 1u);
        }
    }

    // --- final fc on h_SEQ (parity 0) by block 0 ---
    if (b == 0) {
        if (tid == 0) {
            while (__hip_atomic_load(&cnt[(size_t)SEQ * 16], __ATOMIC_RELAXED,
                                     __HIP_MEMORY_SCOPE_AGENT) < (unsigned)NB) {
            }
        }
        __syncthreads();
        __threadfence();
        float s = 0.f;
#pragma unroll
        for (int i = 0; i < 8; i++) {
            float hv = (float)hbuf[(SEQ & 1) * HID + tid * 8 + i];
            s += hv * fcw[tid * 8 + i];
        }
#pragma unroll
        for (int off = 1; off < 64; off <<= 1) s += __shfl_xor(s, off, 64);
        if (lane == 0) red[g] = s;
        __syncthreads();
        if (tid == 0) out[0] = red[0] + red[1] + red[2] + red[3] + fcb[0];
    }
}

// ---------------- launch ----------------
extern "C" void kernel_launch(void* const* d_in, const int* in_sizes, int n_in,
                              void* d_out, int out_size, void* d_ws, size_t ws_size,
                              hipStream_t stream) {
    const float* input = (const float*)d_in[0];  // [SEQ][ISZ]
    const float* W_ih = (const float*)d_in[1];   // [G4H][ISZ]
    const float* W_hh = (const float*)d_in[2];   // [G4H][HID]
    const float* b_ih = (const float*)d_in[3];
    const float* b_hh = (const float*)d_in[4];
    const float* fc_w = (const float*)d_in[5];
    const float* fc_b = (const float*)d_in[6];
    float* out = (float*)d_out;

    char* ws = (char*)d_ws;
    _Float16* xp16 = (_Float16*)ws;               // 134,217,728 B
    _Float16* A16 = (_Float16*)(ws + 134217728);  // 8 MB (dead after gemm)
    _Float16* B16 = (_Float16*)(ws + 142606336);  // 8 MB (dead after gemm)
    // hbuf/cnt overlay the dead A16 region (init_state runs AFTER gemm):
    _Float16* hbuf = (_Float16*)(ws + 134217728);            // 8,192 B
    unsigned* cnt = (unsigned*)(ws + 134217728 + 8192);      // 524,352 B

    cvt_f32_f16<<<(SEQ * ISZ) / 1024, 256, 0, stream>>>(input, A16, SEQ * ISZ);
    cvt_f32_f16<<<(G4H * ISZ) / 1024, 256, 0, stream>>>(W_ih, B16, G4H * ISZ);

    dim3 gg(G4H / 128, SEQ / 128);
    gemm_xproj<<<gg, 256, 0, stream>>>(A16, B16, xp16);

    init_state<<<513, 256, 0, stream>>>(hbuf, cnt);  // after gemm: A16 region is dead

    lstm_persist<<<NB, 256, 0, stream>>>(W_hh, b_ih, b_hh, xp16, fc_w, fc_b,
                                         hbuf, cnt, out);
}

// Round 4
// 54306.049 us; speedup vs baseline: 4.2784x; 4.2784x over previous
//
#include <hip/hip_runtime.h>
#include <hip/hip_bf16.h>

// ---------------- types ----------------
typedef _Float16 half2_t __attribute__((ext_vector_type(2)));
typedef _Float16 half8_t __attribute__((ext_vector_type(8)));
typedef float float4_t __attribute__((ext_vector_type(4)));

#define SEQ   8192
#define ISZ   512
#define HID   2048
#define G4H   8192   // 4*HID
#define NB    256    // persistent blocks (== CU count)

#if __has_builtin(__builtin_amdgcn_fdot2)
#define DOT2(a, b, c) __builtin_amdgcn_fdot2((a), (b), (c), false)
#else
static __device__ __forceinline__ float DOT2(half2_t a, half2_t b, float c) {
    return c + (float)a.x * (float)b.x + (float)a.y * (float)b.y;
}
#endif

// sc1 (device-coherent) accesses via relaxed agent-scope atomics: these lower
// to plain global_load/store_dword{,x2} with the sc1 bit — no buffer_inv /
// buffer_wbl2 cache maintenance, no RMW.
static __device__ __forceinline__ unsigned long long ld_u64(const void* p) {
    return __hip_atomic_load((const unsigned long long*)p, __ATOMIC_RELAXED,
                             __HIP_MEMORY_SCOPE_AGENT);
}
static __device__ __forceinline__ unsigned ld_u32(const void* p) {
    return __hip_atomic_load((const unsigned*)p, __ATOMIC_RELAXED,
                             __HIP_MEMORY_SCOPE_AGENT);
}
static __device__ __forceinline__ void st_u64(void* p, unsigned long long v) {
    __hip_atomic_store((unsigned long long*)p, v, __ATOMIC_RELAXED,
                       __HIP_MEMORY_SCOPE_AGENT);
}
static __device__ __forceinline__ void st_u32(void* p, unsigned v) {
    __hip_atomic_store((unsigned*)p, v, __ATOMIC_RELAXED,
                       __HIP_MEMORY_SCOPE_AGENT);
}
static __device__ __forceinline__ void drain_vm() {
    asm volatile("s_waitcnt vmcnt(0)" ::: "memory");
}

// ---------------- f32 -> f16 convert ----------------
__global__ __launch_bounds__(256) void cvt_f32_f16(const float* __restrict__ in,
                                                   _Float16* __restrict__ out, int n) {
    int i = (blockIdx.x * 256 + threadIdx.x) * 4;
    if (i < n) {
        float4 v = *(const float4*)(in + i);
        out[i + 0] = (_Float16)v.x;
        out[i + 1] = (_Float16)v.y;
        out[i + 2] = (_Float16)v.z;
        out[i + 3] = (_Float16)v.w;
    }
}

// ---------------- init tags + hdata (zeros; tag 0 == "h_0 published") ----------------
__global__ __launch_bounds__(256) void init_state(unsigned* __restrict__ base) {
    int i = blockIdx.x * 256 + threadIdx.x;
    if (i < 2560) base[i] = 0;  // tags[2][256] (2 KB) + hdata[2][256] (8 KB)
}

// ---------------- x_proj GEMM: C[m][n] = sum_k A[m][k]*B[n][k] ----------------
__global__ __launch_bounds__(256) void gemm_xproj(const _Float16* __restrict__ A,  // [SEQ][ISZ]
                                                  const _Float16* __restrict__ B,  // [G4H][ISZ]
                                                  _Float16* __restrict__ C) {      // [SEQ][G4H]
    __shared__ _Float16 As[128 * 40];
    __shared__ _Float16 Bs[128 * 40];
    const int tid = threadIdx.x;
    const int bm = blockIdx.y, bn = blockIdx.x;
    const int wave = tid >> 6, lane = tid & 63;
    const int wr = wave >> 1, wc = wave & 1;
    const int l15 = lane & 15, lq = lane >> 4;

    float4_t acc[4][4];
#pragma unroll
    for (int im = 0; im < 4; im++)
#pragma unroll
        for (int in = 0; in < 4; in++)
#pragma unroll
            for (int r = 0; r < 4; r++) acc[im][in][r] = 0.f;

    for (int kt = 0; kt < ISZ; kt += 32) {
        __syncthreads();
#pragma unroll
        for (int ld = 0; ld < 2; ld++) {
            int c = tid + ld * 256;
            int r = c >> 2, ko = (c & 3) * 8;
            uint4 av = *(const uint4*)(A + (size_t)(bm * 128 + r) * ISZ + kt + ko);
            *(uint4*)(As + r * 40 + ko) = av;
            uint4 bv = *(const uint4*)(B + (size_t)(bn * 128 + r) * ISZ + kt + ko);
            *(uint4*)(Bs + r * 40 + ko) = bv;
        }
        __syncthreads();
        half8_t af[4], bf[4];
#pragma unroll
        for (int im = 0; im < 4; im++)
            af[im] = *(half8_t*)(As + (wr * 64 + im * 16 + l15) * 40 + lq * 8);
#pragma unroll
        for (int in = 0; in < 4; in++)
            bf[in] = *(half8_t*)(Bs + (wc * 64 + in * 16 + l15) * 40 + lq * 8);
#pragma unroll
        for (int im = 0; im < 4; im++)
#pragma unroll
            for (int in = 0; in < 4; in++)
                acc[im][in] = __builtin_amdgcn_mfma_f32_16x16x32_f16(af[im], bf[in], acc[im][in], 0, 0, 0);
    }
#pragma unroll
    for (int im = 0; im < 4; im++) {
        int mg = bm * 128 + wr * 64 + im * 16 + lq * 4;
#pragma unroll
        for (int in = 0; in < 4; in++) {
            int ng = bn * 128 + wc * 64 + in * 16 + l15;
#pragma unroll
            for (int r = 0; r < 4; r++)
                C[(size_t)(mg + r) * G4H + ng] = (_Float16)acc[im][in][r];
        }
    }
}

// ---------------- persistent LSTM recurrence ----------------
// Block b owns h[8b..8b+8); wave g computes gate g rows. Weights in VGPRs (f16).
// Cross-block exchange: per-block 16 B record + 4 B tag, all sc1 (L3-direct).
// No fences, no atomic RMW; one __syncthreads per step.
__global__ __launch_bounds__(256, 1) void lstm_persist(
    const float* __restrict__ Whh,   // [G4H][HID] f32
    const float* __restrict__ b_ih, const float* __restrict__ b_hh,
    const _Float16* __restrict__ xp, // [SEQ][G4H] f16
    const float* __restrict__ fcw, const float* __restrict__ fcb,
    unsigned* __restrict__ tags,     // [2][256] u32
    unsigned long long* __restrict__ hdata,  // [2][256][2] u64 (16 B records)
    float* __restrict__ out) {
    const int b = blockIdx.x, tid = threadIdx.x;
    const int g = tid >> 6, lane = tid & 63;

    __shared__ float gate_lds[4][8];

    // --- prologue: weight slice into registers (f32 -> f16) ---
    half2_t w[8][16];  // 8 rows x 32 cols -> 128 VGPRs
#pragma unroll
    for (int e = 0; e < 8; e++) {
        const float* wp = Whh + (size_t)(g * HID + b * 8 + e) * HID + lane * 32;
#pragma unroll
        for (int i = 0; i < 16; i++) {
            float2 f = *(const float2*)(wp + i * 2);
            half2_t h2;
            h2.x = (_Float16)f.x;
            h2.y = (_Float16)f.y;
            w[e][i] = h2;
        }
    }
    float bias_r = 0.f;
    if (lane < 8) {
        int R = g * HID + b * 8 + lane;
        bias_r = b_ih[R] + b_hh[R];
    }
    float c_reg = 0.f;  // cell state (meaningful for wave 0, lane<8)

    for (int t = 0; t < SEQ; ++t) {
        const unsigned ut = (unsigned)t;
        const int par = t & 1;

        // x_proj prefetch (independent of h; completes during the poll)
        float xpv = 0.f;
        if (lane < 8)
            xpv = (float)xp[(size_t)t * G4H + g * HID + b * 8 + lane];

        // poll: lane j waits for tags 4j..4j+3 (two u64 sc1 loads per round)
        const unsigned* tp = tags + par * 256 + lane * 4;
        bool ok;
        do {
            unsigned long long t01 = ld_u64(tp);
            unsigned long long t23 = ld_u64(tp + 2);
            ok = ((unsigned)t01 >= ut) && ((unsigned)(t01 >> 32) >= ut) &&
                 ((unsigned)t23 >= ut) && ((unsigned)(t23 >> 32) >= ut);
        } while (!__all(ok));
        asm volatile("" ::: "memory");  // no reorder of h loads above the poll

        // gather h slice [lane*32, lane*32+32) straight from L3 records
        union {
            unsigned long long u[8];
            half2_t h2[16];
        } hu;
        const unsigned long long* hp = hdata + (size_t)par * 512 + lane * 8;
#pragma unroll
        for (int i = 0; i < 8; i++) hu.u[i] = ld_u64(hp + i);

        // matvec: 8 rows x 32 cols per thread
        float acc[8];
#pragma unroll
        for (int e = 0; e < 8; e++) {
            float a = 0.f;
#pragma unroll
            for (int i = 0; i < 16; i++) a = DOT2(w[e][i], hu.h2[i], a);
            acc[e] = a;
        }
        // full-wave butterfly reduce (all 8 rows)
#pragma unroll
        for (int off = 1; off < 64; off <<= 1)
#pragma unroll
            for (int e = 0; e < 8; e++) acc[e] += __shfl_xor(acc[e], off, 64);

        if (lane < 8) {
            float v = acc[0];
#pragma unroll
            for (int e = 1; e < 8; e++)
                if (lane == e) v = acc[e];
            gate_lds[g][lane] = v + bias_r + xpv;
        }
        __syncthreads();  // the ONLY barrier: gate_lds ready for wave 0

        if (g == 0) {
            unsigned pk = 0;
            if (lane < 8) {
                float gi = gate_lds[0][lane], gf = gate_lds[1][lane];
                float gg = gate_lds[2][lane], go = gate_lds[3][lane];
                float si = 1.f / (1.f + __expf(-gi));
                float sf = 1.f / (1.f + __expf(-gf));
                float so = 1.f / (1.f + __expf(-go));
                float tg = tanhf(gg);
                c_reg = sf * c_reg + si * tg;
                float h = so * tanhf(c_reg);
                _Float16 hf = (_Float16)h;
                pk = *(unsigned short*)&hf;
            }
            unsigned w0 = __shfl(pk, 0, 64) | (__shfl(pk, 1, 64) << 16);
            unsigned w1 = __shfl(pk, 2, 64) | (__shfl(pk, 3, 64) << 16);
            unsigned w2 = __shfl(pk, 4, 64) | (__shfl(pk, 5, 64) << 16);
            unsigned w3 = __shfl(pk, 6, 64) | (__shfl(pk, 7, 64) << 16);
            if (lane == 0) {
                int np = (t + 1) & 1;
                unsigned long long* dp = hdata + (size_t)np * 512 + b * 2;
                st_u64(dp, (unsigned long long)w0 | ((unsigned long long)w1 << 32));
                st_u64(dp + 1, (unsigned long long)w2 | ((unsigned long long)w3 << 32));
                drain_vm();  // record visible at L3 before the tag
                st_u32(tags + np * 256 + b, ut + 1);
            }
        }
        // waves 1-3 proceed; their next-step poll (includes OUR tag) is the
        // implicit barrier protecting gate_lds against early rewrite.
    }

    // --- final fc on h_SEQ by block 0, wave 0 ---
    if (b == 0 && g == 0) {
        const unsigned* tp = tags + (SEQ & 1) * 256 + lane * 4;
        bool ok;
        do {
            unsigned long long t01 = ld_u64(tp);
            unsigned long long t23 = ld_u64(tp + 2);
            ok = ((unsigned)t01 >= (unsigned)SEQ) && ((unsigned)(t01 >> 32) >= (unsigned)SEQ) &&
                 ((unsigned)t23 >= (unsigned)SEQ) && ((unsigned)(t23 >> 32) >= (unsigned)SEQ);
        } while (!__all(ok));
        asm volatile("" ::: "memory");
        union {
            unsigned long long u[8];
            half2_t h2[16];
        } hu;
        const unsigned long long* hp = hdata + (size_t)(SEQ & 1) * 512 + lane * 8;
#pragma unroll
        for (int i = 0; i < 8; i++) hu.u[i] = ld_u64(hp + i);
        float s = 0.f;
        const float* fw = fcw + lane * 32;
#pragma unroll
        for (int i = 0; i < 16; i++)
            s += (float)hu.h2[i].x * fw[2 * i] + (float)hu.h2[i].y * fw[2 * i + 1];
#pragma unroll
        for (int off = 1; off < 64; off <<= 1) s += __shfl_xor(s, off, 64);
        if (lane == 0) out[0] = s + fcb[0];
    }
}

// ---------------- launch ----------------
extern "C" void kernel_launch(void* const* d_in, const int* in_sizes, int n_in,
                              void* d_out, int out_size, void* d_ws, size_t ws_size,
                              hipStream_t stream) {
    const float* input = (const float*)d_in[0];  // [SEQ][ISZ]
    const float* W_ih = (const float*)d_in[1];   // [G4H][ISZ]
    const float* W_hh = (const float*)d_in[2];   // [G4H][HID]
    const float* b_ih = (const float*)d_in[3];
    const float* b_hh = (const float*)d_in[4];
    const float* fc_w = (const float*)d_in[5];
    const float* fc_b = (const float*)d_in[6];
    float* out = (float*)d_out;

    char* ws = (char*)d_ws;
    _Float16* xp16 = (_Float16*)ws;               // 134,217,728 B
    _Float16* A16 = (_Float16*)(ws + 134217728);  // 8 MB (dead after gemm)
    _Float16* B16 = (_Float16*)(ws + 142606336);  // 8 MB (dead after gemm)
    // tags/hdata overlay the dead A16 region (init_state runs AFTER gemm):
    unsigned* tags = (unsigned*)(ws + 134217728);                      // 2,048 B
    unsigned long long* hdata = (unsigned long long*)(ws + 134217728 + 2048);  // 8,192 B

    cvt_f32_f16<<<(SEQ * ISZ) / 1024, 256, 0, stream>>>(input, A16, SEQ * ISZ);
    cvt_f32_f16<<<(G4H * ISZ) / 1024, 256, 0, stream>>>(W_ih, B16, G4H * ISZ);

    dim3 gg(G4H / 128, SEQ / 128);
    gemm_xproj<<<gg, 256, 0, stream>>>(A16, B16, xp16);

    init_state<<<10, 256, 0, stream>>>(tags);  // zeros tags + hdata (contiguous)

    lstm_persist<<<NB, 256, 0, stream>>>(W_hh, b_ih, b_hh, xp16, fc_w, fc_b,
                                         tags, hdata, out);
}

// Round 5
// 20496.823 us; speedup vs baseline: 11.3357x; 2.6495x over previous
//
#include <hip/hip_runtime.h>
#include <hip/hip_bf16.h>

// ---------------- types ----------------
typedef _Float16 half2_t __attribute__((ext_vector_type(2)));
typedef _Float16 half8_t __attribute__((ext_vector_type(8)));
typedef float float4_t __attribute__((ext_vector_type(4)));

#define SEQ   8192
#define ISZ   512
#define HID   2048
#define G4H   8192   // 4*HID
#define NB    256    // persistent blocks (== CU count)

#if __has_builtin(__builtin_amdgcn_fdot2)
#define DOT2(a, b, c) __builtin_amdgcn_fdot2((a), (b), (c), false)
#else
static __device__ __forceinline__ float DOT2(half2_t a, half2_t b, float c) {
    return c + (float)a.x * (float)b.x + (float)a.y * (float)b.y;
}
#endif

#if __has_builtin(__builtin_amdgcn_rcpf)
#define RCP(x) __builtin_amdgcn_rcpf(x)
#else
#define RCP(x) (1.0f / (x))
#endif

// relaxed agent-scope (sc1, device-coherent) accesses — no fences, no RMW
static __device__ __forceinline__ unsigned long long ld_u64(const void* p) {
    return __hip_atomic_load((const unsigned long long*)p, __ATOMIC_RELAXED,
                             __HIP_MEMORY_SCOPE_AGENT);
}
static __device__ __forceinline__ void st_u64(void* p, unsigned long long v) {
    __hip_atomic_store((unsigned long long*)p, v, __ATOMIC_RELAXED,
                       __HIP_MEMORY_SCOPE_AGENT);
}

// ---------------- f32 -> f16 convert ----------------
__global__ __launch_bounds__(256) void cvt_f32_f16(const float* __restrict__ in,
                                                   _Float16* __restrict__ out, int n) {
    int i = (blockIdx.x * 256 + threadIdx.x) * 4;
    if (i < n) {
        float4 v = *(const float4*)(in + i);
        out[i + 0] = (_Float16)v.x;
        out[i + 1] = (_Float16)v.y;
        out[i + 2] = (_Float16)v.z;
        out[i + 3] = (_Float16)v.w;
    }
}

// ---------------- init words (zero => {h=0, tag=0} == "h_0 valid") ----------------
__global__ __launch_bounds__(256) void init_state(unsigned long long* __restrict__ words) {
    int i = blockIdx.x * 256 + threadIdx.x;
    if (i < 2048) words[i] = 0ull;  // words[2][1024]
}

// ---------------- x_proj GEMM: C[m][n] = sum_k A[m][k]*B[n][k] ----------------
__global__ __launch_bounds__(256) void gemm_xproj(const _Float16* __restrict__ A,  // [SEQ][ISZ]
                                                  const _Float16* __restrict__ B,  // [G4H][ISZ]
                                                  _Float16* __restrict__ C) {      // [SEQ][G4H]
    __shared__ _Float16 As[128 * 40];
    __shared__ _Float16 Bs[128 * 40];
    const int tid = threadIdx.x;
    const int bm = blockIdx.y, bn = blockIdx.x;
    const int wave = tid >> 6, lane = tid & 63;
    const int wr = wave >> 1, wc = wave & 1;
    const int l15 = lane & 15, lq = lane >> 4;

    float4_t acc[4][4];
#pragma unroll
    for (int im = 0; im < 4; im++)
#pragma unroll
        for (int in = 0; in < 4; in++)
#pragma unroll
            for (int r = 0; r < 4; r++) acc[im][in][r] = 0.f;

    for (int kt = 0; kt < ISZ; kt += 32) {
        __syncthreads();
#pragma unroll
        for (int ld = 0; ld < 2; ld++) {
            int c = tid + ld * 256;
            int r = c >> 2, ko = (c & 3) * 8;
            uint4 av = *(const uint4*)(A + (size_t)(bm * 128 + r) * ISZ + kt + ko);
            *(uint4*)(As + r * 40 + ko) = av;
            uint4 bv = *(const uint4*)(B + (size_t)(bn * 128 + r) * ISZ + kt + ko);
            *(uint4*)(Bs + r * 40 + ko) = bv;
        }
        __syncthreads();
        half8_t af[4], bf[4];
#pragma unroll
        for (int im = 0; im < 4; im++)
            af[im] = *(half8_t*)(As + (wr * 64 + im * 16 + l15) * 40 + lq * 8);
#pragma unroll
        for (int in = 0; in < 4; in++)
            bf[in] = *(half8_t*)(Bs + (wc * 64 + in * 16 + l15) * 40 + lq * 8);
#pragma unroll
        for (int im = 0; im < 4; im++)
#pragma unroll
            for (int in = 0; in < 4; in++)
                acc[im][in] = __builtin_amdgcn_mfma_f32_16x16x32_f16(af[im], bf[in], acc[im][in], 0, 0, 0);
    }
#pragma unroll
    for (int im = 0; im < 4; im++) {
        int mg = bm * 128 + wr * 64 + im * 16 + lq * 4;
#pragma unroll
        for (int in = 0; in < 4; in++) {
            int ng = bn * 128 + wc * 64 + in * 16 + l15;
#pragma unroll
            for (int r = 0; r < 4; r++)
                C[(size_t)(mg + r) * G4H + ng] = (_Float16)acc[im][in][r];
        }
    }
}

// ---------------- persistent LSTM recurrence ----------------
// Exchange unit: u64 word = {tag32 | h[2i+1] | h[2i]}. Block b owns words
// [4b..4b+4) per parity. Self-validating: one load returns data + validity,
// so the tag->data second round trip and producer drain are gone.
// Wave g polls/stages only blocks [64g..64g+64) (lane j -> block 64g+j).
__global__ __launch_bounds__(256, 1) void lstm_persist(
    const float* __restrict__ Whh,   // [G4H][HID] f32
    const float* __restrict__ b_ih, const float* __restrict__ b_hh,
    const _Float16* __restrict__ xp, // [SEQ][G4H] f16
    const float* __restrict__ fcw, const float* __restrict__ fcb,
    unsigned long long* __restrict__ words,  // [2][1024]
    float* __restrict__ out) {
    const int b = blockIdx.x, tid = threadIdx.x;
    const int g = tid >> 6, lane = tid & 63;
    const int myblk = g * 64 + lane;  // block this lane polls/stages

    __shared__ float gate_lds[4][8];
    __shared__ unsigned long long h_lds_u64[576];  // 64 slices x 72 B (stride 18 dwords)
    unsigned* h_lds32 = (unsigned*)h_lds_u64;

    // --- prologue: weight slice into registers (f32 -> f16) ---
    half2_t w[8][16];  // rows g*HID+b*8+e, cols [lane*32, lane*32+32)
#pragma unroll
    for (int e = 0; e < 8; e++) {
        const float* wp = Whh + (size_t)(g * HID + b * 8 + e) * HID + lane * 32;
#pragma unroll
        for (int i = 0; i < 16; i++) {
            float2 f = *(const float2*)(wp + i * 2);
            half2_t h2;
            h2.x = (_Float16)f.x;
            h2.y = (_Float16)f.y;
            w[e][i] = h2;
        }
    }
    float bias_r = 0.f;
    if (lane < 8) {
        int R = g * HID + b * 8 + lane;
        bias_r = b_ih[R] + b_hh[R];
    }
    float c_reg = 0.f;  // cell state (wave 0, lanes 0-7)

    const int s_dw = (myblk >> 2) * 18 + (myblk & 3) * 4;  // LDS stage dst (dwords)

    for (int t = 0; t < SEQ; ++t) {
        const unsigned ut = (unsigned)t;
        const int par = t & 1;

        // x_proj prefetch (independent of h; overlaps the poll)
        float xpv = 0.f;
        if (lane < 8)
            xpv = (float)xp[(size_t)t * G4H + g * HID + b * 8 + lane];

        // poll own 4 self-validating words (32 B/lane)
        const unsigned long long* wp = words + (size_t)par * 1024 + myblk * 4;
        unsigned long long v0, v1, v2, v3;
        for (;;) {
            v0 = ld_u64(wp + 0);
            v1 = ld_u64(wp + 1);
            v2 = ld_u64(wp + 2);
            v3 = ld_u64(wp + 3);
            bool ok = ((unsigned)(v0 >> 32) >= ut) && ((unsigned)(v1 >> 32) >= ut) &&
                      ((unsigned)(v2 >> 32) >= ut) && ((unsigned)(v3 >> 32) >= ut);
            if (__all(ok)) break;
            __builtin_amdgcn_s_sleep(1);  // backoff: halve poll flood
        }

        // stage 8 halves of block myblk into LDS
        h_lds32[s_dw + 0] = (unsigned)v0;
        h_lds32[s_dw + 1] = (unsigned)v1;
        h_lds32[s_dw + 2] = (unsigned)v2;
        h_lds32[s_dw + 3] = (unsigned)v3;
        __syncthreads();  // B1: h_t fully staged

        // read slice [lane*32, lane*32+32) from LDS (stride-72 slices, ~2-4 way banks)
        union {
            unsigned long long u[8];
            half2_t h2[16];
        } hu;
        const unsigned long long* hp =
            (const unsigned long long*)((const char*)h_lds_u64 + 72 * lane);
#pragma unroll
        for (int i = 0; i < 8; i++) hu.u[i] = hp[i];

        // matvec: 8 rows x 32 cols per lane
        float acc[8];
#pragma unroll
        for (int e = 0; e < 8; e++) {
            float a = 0.f;
#pragma unroll
            for (int i = 0; i < 16; i++) a = DOT2(w[e][i], hu.h2[i], a);
            acc[e] = a;
        }
        // two-phase reduce: 24 shfl + 7 select + 3 shfl
#pragma unroll
        for (int off = 1; off <= 4; off <<= 1)
#pragma unroll
            for (int e = 0; e < 8; e++) acc[e] += __shfl_xor(acc[e], off, 64);
        float u;
        {
            int s = lane & 7;
            float u01 = (s & 1) ? acc[1] : acc[0];
            float u23 = (s & 1) ? acc[3] : acc[2];
            float u45 = (s & 1) ? acc[5] : acc[4];
            float u67 = (s & 1) ? acc[7] : acc[6];
            float ua = (s & 2) ? u23 : u01;
            float ub = (s & 2) ? u67 : u45;
            u = (s & 4) ? ub : ua;
        }
        u += __shfl_xor(u, 8, 64);
        u += __shfl_xor(u, 16, 64);
        u += __shfl_xor(u, 32, 64);

        if (lane < 8) gate_lds[g][lane] = u + bias_r + xpv;
        __syncthreads();  // B2: all 4 gate rows ready

        if (g == 0) {
            unsigned pk = 0;
            if (lane < 8) {
                float gi = gate_lds[0][lane], gf = gate_lds[1][lane];
                float gg = gate_lds[2][lane], go = gate_lds[3][lane];
                float si = RCP(1.f + __expf(-gi));
                float sf = RCP(1.f + __expf(-gf));
                float so = RCP(1.f + __expf(-go));
                float tg = 1.f - 2.f * RCP(1.f + __expf(2.f * gg));
                c_reg = sf * c_reg + si * tg;
                float tc = 1.f - 2.f * RCP(1.f + __expf(2.f * c_reg));
                float h = so * tc;
                _Float16 hf = (_Float16)h;
                pk = *(unsigned short*)&hf;
            }
            unsigned lo = __shfl(pk, 2 * lane, 64) | (__shfl(pk, 2 * lane + 1, 64) << 16);
            if (lane < 4) {
                unsigned long long wword =
                    (unsigned long long)lo | ((unsigned long long)(ut + 1) << 32);
                st_u64(words + (size_t)((t + 1) & 1) * 1024 + b * 4 + lane, wword);
            }
        }
        // waves 1-3 move on; their next poll (incl. our own words) is the
        // implicit barrier protecting h_lds/gate_lds from early rewrite.
    }

    // --- final fc on h_SEQ (parity 0) by block 0 ---
    if (b == 0) {
        const unsigned long long* wp = words + (size_t)((SEQ & 1)) * 1024 + myblk * 4;
        unsigned long long v0, v1, v2, v3;
        for (;;) {
            v0 = ld_u64(wp + 0);
            v1 = ld_u64(wp + 1);
            v2 = ld_u64(wp + 2);
            v3 = ld_u64(wp + 3);
            bool ok = ((unsigned)(v0 >> 32) >= (unsigned)SEQ) &&
                      ((unsigned)(v1 >> 32) >= (unsigned)SEQ) &&
                      ((unsigned)(v2 >> 32) >= (unsigned)SEQ) &&
                      ((unsigned)(v3 >> 32) >= (unsigned)SEQ);
            if (__all(ok)) break;
            __builtin_amdgcn_s_sleep(1);
        }
        h_lds32[s_dw + 0] = (unsigned)v0;
        h_lds32[s_dw + 1] = (unsigned)v1;
        h_lds32[s_dw + 2] = (unsigned)v2;
        h_lds32[s_dw + 3] = (unsigned)v3;
        __syncthreads();
        if (g == 0) {
            union {
                unsigned long long u[8];
                half2_t h2[16];
            } hu;
            const unsigned long long* hp =
                (const unsigned long long*)((const char*)h_lds_u64 + 72 * lane);
#pragma unroll
            for (int i = 0; i < 8; i++) hu.u[i] = hp[i];
            float s = 0.f;
            const float* fw = fcw + lane * 32;
#pragma unroll
            for (int i = 0; i < 16; i++)
                s += (float)hu.h2[i].x * fw[2 * i] + (float)hu.h2[i].y * fw[2 * i + 1];
#pragma unroll
            for (int off = 1; off < 64; off <<= 1) s += __shfl_xor(s, off, 64);
            if (lane == 0) out[0] = s + fcb[0];
        }
    }
}

// ---------------- launch ----------------
extern "C" void kernel_launch(void* const* d_in, const int* in_sizes, int n_in,
                              void* d_out, int out_size, void* d_ws, size_t ws_size,
                              hipStream_t stream) {
    const float* input = (const float*)d_in[0];  // [SEQ][ISZ]
    const float* W_ih = (const float*)d_in[1];   // [G4H][ISZ]
    const float* W_hh = (const float*)d_in[2];   // [G4H][HID]
    const float* b_ih = (const float*)d_in[3];
    const float* b_hh = (const float*)d_in[4];
    const float* fc_w = (const float*)d_in[5];
    const float* fc_b = (const float*)d_in[6];
    float* out = (float*)d_out;

    char* ws = (char*)d_ws;
    _Float16* xp16 = (_Float16*)ws;               // 134,217,728 B
    _Float16* A16 = (_Float16*)(ws + 134217728);  // 8 MB (dead after gemm)
    _Float16* B16 = (_Float16*)(ws + 142606336);  // 8 MB (dead after gemm)
    // words overlay the dead A16 region (init_state runs AFTER gemm):
    unsigned long long* words = (unsigned long long*)(ws + 134217728);  // 16,384 B

    cvt_f32_f16<<<(SEQ * ISZ) / 1024, 256, 0, stream>>>(input, A16, SEQ * ISZ);
    cvt_f32_f16<<<(G4H * ISZ) / 1024, 256, 0, stream>>>(W_ih, B16, G4H * ISZ);

    dim3 gg(G4H / 128, SEQ / 128);
    gemm_xproj<<<gg, 256, 0, stream>>>(A16, B16, xp16);

    init_state<<<8, 256, 0, stream>>>(words);  // after gemm: A16 region is dead

    lstm_persist<<<NB, 256, 0, stream>>>(W_hh, b_ih, b_hh, xp16, fc_w, fc_b,
                                         words, out);
}

// Round 6
// 17118.805 us; speedup vs baseline: 13.5725x; 1.1973x over previous
//
#include <hip/hip_runtime.h>
#include <hip/hip_bf16.h>

// ---------------- types ----------------
typedef _Float16 half2_t __attribute__((ext_vector_type(2)));
typedef _Float16 half8_t __attribute__((ext_vector_type(8)));
typedef float float4_t __attribute__((ext_vector_type(4)));

#define SEQ   8192
#define ISZ   512
#define HID   2048
#define G4H   8192   // 4*HID
#define NB    256    // persistent blocks (== CU count)

#if __has_builtin(__builtin_amdgcn_fdot2)
#define DOT2(a, b, c) __builtin_amdgcn_fdot2((a), (b), (c), false)
#else
static __device__ __forceinline__ float DOT2(half2_t a, half2_t b, float c) {
    return c + (float)a.x * (float)b.x + (float)a.y * (float)b.y;
}
#endif

#if __has_builtin(__builtin_amdgcn_rcpf)
#define RCP(x) __builtin_amdgcn_rcpf(x)
#else
#define RCP(x) (1.0f / (x))
#endif

// relaxed agent-scope (sc1, device-coherent) accesses — no fences, no RMW
static __device__ __forceinline__ unsigned long long ld_u64(const void* p) {
    return __hip_atomic_load((const unsigned long long*)p, __ATOMIC_RELAXED,
                             __HIP_MEMORY_SCOPE_AGENT);
}
static __device__ __forceinline__ void st_u64(void* p, unsigned long long v) {
    __hip_atomic_store((unsigned long long*)p, v, __ATOMIC_RELAXED,
                       __HIP_MEMORY_SCOPE_AGENT);
}

// ---------------- f32 -> f16 convert ----------------
__global__ __launch_bounds__(256) void cvt_f32_f16(const float* __restrict__ in,
                                                   _Float16* __restrict__ out, int n) {
    int i = (blockIdx.x * 256 + threadIdx.x) * 4;
    if (i < n) {
        float4 v = *(const float4*)(in + i);
        out[i + 0] = (_Float16)v.x;
        out[i + 1] = (_Float16)v.y;
        out[i + 2] = (_Float16)v.z;
        out[i + 3] = (_Float16)v.w;
    }
}

// ---------------- init words (zero => {h=0, tag=0} == "h_0 valid") ----------------
__global__ __launch_bounds__(256) void init_state(unsigned long long* __restrict__ words) {
    int i = blockIdx.x * 256 + threadIdx.x;
    if (i < 4096) words[i] = 0ull;  // words[2][256][8] (each block: own 64-B line)
}

// ---------------- x_proj GEMM: C[m][n] = sum_k A[m][k]*B[n][k] ----------------
__global__ __launch_bounds__(256) void gemm_xproj(const _Float16* __restrict__ A,  // [SEQ][ISZ]
                                                  const _Float16* __restrict__ B,  // [G4H][ISZ]
                                                  _Float16* __restrict__ C) {      // [SEQ][G4H]
    __shared__ _Float16 As[128 * 40];
    __shared__ _Float16 Bs[128 * 40];
    const int tid = threadIdx.x;
    const int bm = blockIdx.y, bn = blockIdx.x;
    const int wave = tid >> 6, lane = tid & 63;
    const int wr = wave >> 1, wc = wave & 1;
    const int l15 = lane & 15, lq = lane >> 4;

    float4_t acc[4][4];
#pragma unroll
    for (int im = 0; im < 4; im++)
#pragma unroll
        for (int in = 0; in < 4; in++)
#pragma unroll
            for (int r = 0; r < 4; r++) acc[im][in][r] = 0.f;

    for (int kt = 0; kt < ISZ; kt += 32) {
        __syncthreads();
#pragma unroll
        for (int ld = 0; ld < 2; ld++) {
            int c = tid + ld * 256;
            int r = c >> 2, ko = (c & 3) * 8;
            uint4 av = *(const uint4*)(A + (size_t)(bm * 128 + r) * ISZ + kt + ko);
            *(uint4*)(As + r * 40 + ko) = av;
            uint4 bv = *(const uint4*)(B + (size_t)(bn * 128 + r) * ISZ + kt + ko);
            *(uint4*)(Bs + r * 40 + ko) = bv;
        }
        __syncthreads();
        half8_t af[4], bf[4];
#pragma unroll
        for (int im = 0; im < 4; im++)
            af[im] = *(half8_t*)(As + (wr * 64 + im * 16 + l15) * 40 + lq * 8);
#pragma unroll
        for (int in = 0; in < 4; in++)
            bf[in] = *(half8_t*)(Bs + (wc * 64 + in * 16 + l15) * 40 + lq * 8);
#pragma unroll
        for (int im = 0; im < 4; im++)
#pragma unroll
            for (int in = 0; in < 4; in++)
                acc[im][in] = __builtin_amdgcn_mfma_f32_16x16x32_f16(af[im], bf[in], acc[im][in], 0, 0, 0);
    }
#pragma unroll
    for (int im = 0; im < 4; im++) {
        int mg = bm * 128 + wr * 64 + im * 16 + lq * 4;
#pragma unroll
        for (int in = 0; in < 4; in++) {
            int ng = bn * 128 + wc * 64 + in * 16 + l15;
#pragma unroll
            for (int r = 0; r < 4; r++)
                C[(size_t)(mg + r) * G4H + ng] = (_Float16)acc[im][in][r];
        }
    }
}

// ---------------- persistent LSTM recurrence ----------------
// Block b owns h[8b..8b+8). Wave g owns ALL FOUR gates of elements {2g, 2g+1}
// (rows r=0..7: gate=r>>1, elem=2g+(r&1)), so each wave computes its own gates
// and publishes its own self-validating word — ONE barrier per step, no B2.
// Exchange word = {tag32 | h[2e+1] f16 | h[2e] f16}; block b word g at
// words[par][b*8+g] (64-B line per block). Poll rotation: lane j of block b
// polls block 64g+((j+b)&63) — spreads the reader herd across L3 lines.
__global__ __launch_bounds__(256, 1) void lstm_persist(
    const float* __restrict__ Whh,   // [G4H][HID] f32
    const float* __restrict__ b_ih, const float* __restrict__ b_hh,
    const _Float16* __restrict__ xp, // [SEQ][G4H] f16
    const float* __restrict__ fcw, const float* __restrict__ fcb,
    unsigned long long* __restrict__ words,  // [2][256][8]
    float* __restrict__ out) {
    const int b = blockIdx.x, tid = threadIdx.x;
    const int g = tid >> 6, lane = tid & 63;
    const int pblk = (g << 6) | ((lane + b) & 63);  // block this lane polls/stages

    __shared__ unsigned long long h_lds_u64[2][576];  // parity x (64 slices x 72 B)

    // --- prologue: weight slice into registers (f32 -> f16) ---
    // row r (r=0..7): global row = (r>>1)*HID + b*8 + 2*g + (r&1); cols [lane*32,+32)
    half2_t w[8][16];
#pragma unroll
    for (int r = 0; r < 8; r++) {
        const float* wp =
            Whh + (size_t)((r >> 1) * HID + b * 8 + 2 * g + (r & 1)) * HID + lane * 32;
#pragma unroll
        for (int i = 0; i < 16; i++) {
            float2 f = *(const float2*)(wp + i * 2);
            half2_t h2;
            h2.x = (_Float16)f.x;
            h2.y = (_Float16)f.y;
            w[r][i] = h2;
        }
    }
    float bias_r = 0.f;
    int myrow = 0;
    if (lane < 8) {
        myrow = ((lane >> 1) & 3) * HID + b * 8 + 2 * g + (lane & 1);
        bias_r = b_ih[myrow] + b_hh[myrow];
    }
    float c_reg = 0.f;  // cell state of elem 2g+(lane&1), redundant per lane group

    const int s_dw = (pblk >> 2) * 18 + (pblk & 3) * 4;  // LDS stage dst (dwords)

    for (int t = 0; t < SEQ; ++t) {
        const unsigned ut = (unsigned)t;
        const int par = t & 1;

        // x_proj prefetch (independent of h; overlaps the poll)
        float xpv = 0.f;
        if (lane < 8) xpv = (float)xp[(size_t)t * G4H + myrow];

        // poll own block's 4 self-validating words (32 B/lane)
        const unsigned long long* wp = words + (size_t)par * 2048 + pblk * 8;
        unsigned long long v0, v1, v2, v3;
        for (;;) {
            v0 = ld_u64(wp + 0);
            v1 = ld_u64(wp + 1);
            v2 = ld_u64(wp + 2);
            v3 = ld_u64(wp + 3);
            bool ok = ((unsigned)(v0 >> 32) >= ut) && ((unsigned)(v1 >> 32) >= ut) &&
                      ((unsigned)(v2 >> 32) >= ut) && ((unsigned)(v3 >> 32) >= ut);
            if (__all(ok)) break;
            __builtin_amdgcn_s_sleep(1);
        }

        // stage 8 halves of block pblk into parity LDS buffer
        unsigned* h32 = (unsigned*)h_lds_u64[par];
        h32[s_dw + 0] = (unsigned)v0;
        h32[s_dw + 1] = (unsigned)v1;
        h32[s_dw + 2] = (unsigned)v2;
        h32[s_dw + 3] = (unsigned)v3;
        __syncthreads();  // the ONLY barrier: h_t fully staged

        // read slice [lane*32, lane*32+32) from LDS
        union {
            unsigned long long u[8];
            half2_t h2[16];
        } hu;
        const unsigned long long* hp =
            (const unsigned long long*)((const char*)h_lds_u64[par] + 72 * lane);
#pragma unroll
        for (int i = 0; i < 8; i++) hu.u[i] = hp[i];

        // matvec: 8 rows x 32 cols per lane
        float acc[8];
#pragma unroll
        for (int r = 0; r < 8; r++) {
            float a = 0.f;
#pragma unroll
            for (int i = 0; i < 16; i++) a = DOT2(w[r][i], hu.h2[i], a);
            acc[r] = a;
        }
        // two-phase reduce: lane s ends with row (s&7)'s full sum
#pragma unroll
        for (int off = 1; off <= 4; off <<= 1)
#pragma unroll
            for (int r = 0; r < 8; r++) acc[r] += __shfl_xor(acc[r], off, 64);
        float u;
        {
            int s = lane & 7;
            float u01 = (s & 1) ? acc[1] : acc[0];
            float u23 = (s & 1) ? acc[3] : acc[2];
            float u45 = (s & 1) ? acc[5] : acc[4];
            float u67 = (s & 1) ? acc[7] : acc[6];
            float ua = (s & 2) ? u23 : u01;
            float ub = (s & 2) ? u67 : u45;
            u = (s & 4) ? ub : ua;
        }
        u += __shfl_xor(u, 8, 64);
        u += __shfl_xor(u, 16, 64);
        u += __shfl_xor(u, 32, 64);
        u += bias_r + xpv;  // valid in lanes 0..7 (sources of the gate shfls)

        // gates: rows [i_e0,i_e1,f_e0,f_e1,g_e0,g_e1,o_e0,o_e1] in lanes 0..7
        {
            int base = lane & 1;  // elem group: even lanes -> e0, odd -> e1
            float gi = __shfl(u, base + 0, 64);
            float gf = __shfl(u, base + 2, 64);
            float gg = __shfl(u, base + 4, 64);
            float go = __shfl(u, base + 6, 64);
            float si = RCP(1.f + __expf(-gi));
            float sf = RCP(1.f + __expf(-gf));
            float so = RCP(1.f + __expf(-go));
            float tg = 1.f - 2.f * RCP(1.f + __expf(2.f * gg));
            c_reg = sf * c_reg + si * tg;
            float tc = 1.f - 2.f * RCP(1.f + __expf(2.f * c_reg));
            float h = so * tc;
            _Float16 hf = (_Float16)h;
            unsigned pk = *(unsigned short*)&hf;
            unsigned pk1 = __shfl(pk, 1, 64);  // lane 0 grabs h_e1 from lane 1
            if (lane == 0) {
                unsigned lo = pk | (pk1 << 16);
                unsigned long long wword =
                    (unsigned long long)lo | ((unsigned long long)(ut + 1) << 32);
                st_u64(words + (size_t)((t + 1) & 1) * 2048 + b * 8 + g, wword);
            }
        }
        // all waves proceed independently; parity-double-buffered h_lds +
        // B1 barrier ordering make cross-step LDS reuse race-free.
    }

    // --- final fc on h_SEQ (parity 0) by block 0 ---
    if (b == 0) {
        const int par = SEQ & 1;
        const unsigned long long* wp = words + (size_t)par * 2048 + pblk * 8;
        unsigned long long v0, v1, v2, v3;
        for (;;) {
            v0 = ld_u64(wp + 0);
            v1 = ld_u64(wp + 1);
            v2 = ld_u64(wp + 2);
            v3 = ld_u64(wp + 3);
            bool ok = ((unsigned)(v0 >> 32) >= (unsigned)SEQ) &&
                      ((unsigned)(v1 >> 32) >= (unsigned)SEQ) &&
                      ((unsigned)(v2 >> 32) >= (unsigned)SEQ) &&
                      ((unsigned)(v3 >> 32) >= (unsigned)SEQ);
            if (__all(ok)) break;
            __builtin_amdgcn_s_sleep(1);
        }
        unsigned* h32 = (unsigned*)h_lds_u64[par];
        h32[s_dw + 0] = (unsigned)v0;
        h32[s_dw + 1] = (unsigned)v1;
        h32[s_dw + 2] = (unsigned)v2;
        h32[s_dw + 3] = (unsigned)v3;
        __syncthreads();
        if (g == 0) {
            union {
                unsigned long long u[8];
                half2_t h2[16];
            } hu;
            const unsigned long long* hp =
                (const unsigned long long*)((const char*)h_lds_u64[par] + 72 * lane);
#pragma unroll
            for (int i = 0; i < 8; i++) hu.u[i] = hp[i];
            float s = 0.f;
            const float* fw = fcw + lane * 32;
#pragma unroll
            for (int i = 0; i < 16; i++)
                s += (float)hu.h2[i].x * fw[2 * i] + (float)hu.h2[i].y * fw[2 * i + 1];
#pragma unroll
            for (int off = 1; off < 64; off <<= 1) s += __shfl_xor(s, off, 64);
            if (lane == 0) out[0] = s + fcb[0];
        }
    }
}

// ---------------- launch ----------------
extern "C" void kernel_launch(void* const* d_in, const int* in_sizes, int n_in,
                              void* d_out, int out_size, void* d_ws, size_t ws_size,
                              hipStream_t stream) {
    const float* input = (const float*)d_in[0];  // [SEQ][ISZ]
    const float* W_ih = (const float*)d_in[1];   // [G4H][ISZ]
    const float* W_hh = (const float*)d_in[2];   // [G4H][HID]
    const float* b_ih = (const float*)d_in[3];
    const float* b_hh = (const float*)d_in[4];
    const float* fc_w = (const float*)d_in[5];
    const float* fc_b = (const float*)d_in[6];
    float* out = (float*)d_out;

    char* ws = (char*)d_ws;
    _Float16* xp16 = (_Float16*)ws;               // 134,217,728 B
    _Float16* A16 = (_Float16*)(ws + 134217728);  // 8 MB (dead after gemm)
    _Float16* B16 = (_Float16*)(ws + 142606336);  // 8 MB (dead after gemm)
    // words overlay the dead A16 region (init_state runs AFTER gemm):
    unsigned long long* words = (unsigned long long*)(ws + 134217728);  // 32,768 B

    cvt_f32_f16<<<(SEQ * ISZ) / 1024, 256, 0, stream>>>(input, A16, SEQ * ISZ);
    cvt_f32_f16<<<(G4H * ISZ) / 1024, 256, 0, stream>>>(W_ih, B16, G4H * ISZ);

    dim3 gg(G4H / 128, SEQ / 128);
    gemm_xproj<<<gg, 256, 0, stream>>>(A16, B16, xp16);

    init_state<<<16, 256, 0, stream>>>(words);  // after gemm: A16 region is dead

    lstm_persist<<<NB, 256, 0, stream>>>(W_hh, b_ih, b_hh, xp16, fc_w, fc_b,
                                         words, out);
}

// Round 7
// 15046.159 us; speedup vs baseline: 15.4422x; 1.1378x over previous
//
#include <hip/hip_runtime.h>
#include <hip/hip_bf16.h>

// ---------------- types ----------------
typedef _Float16 half2_t __attribute__((ext_vector_type(2)));
typedef _Float16 half8_t __attribute__((ext_vector_type(8)));
typedef float float4_t __attribute__((ext_vector_type(4)));

#define SEQ   8192
#define ISZ   512
#define HID   2048
#define G4H   8192   // 4*HID
#define NB    256    // persistent blocks (== CU count)

#if __has_builtin(__builtin_amdgcn_fdot2)
#define DOT2(a, b, c) __builtin_amdgcn_fdot2((a), (b), (c), false)
#else
static __device__ __forceinline__ float DOT2(half2_t a, half2_t b, float c) {
    return c + (float)a.x * (float)b.x + (float)a.y * (float)b.y;
}
#endif

#if __has_builtin(__builtin_amdgcn_rcpf)
#define RCP(x) __builtin_amdgcn_rcpf(x)
#else
#define RCP(x) (1.0f / (x))
#endif

// relaxed agent-scope (sc1, device-coherent) accesses — no fences, no RMW
static __device__ __forceinline__ unsigned long long ld_u64(const void* p) {
    return __hip_atomic_load((const unsigned long long*)p, __ATOMIC_RELAXED,
                             __HIP_MEMORY_SCOPE_AGENT);
}
static __device__ __forceinline__ void st_u64(void* p, unsigned long long v) {
    __hip_atomic_store((unsigned long long*)p, v, __ATOMIC_RELAXED,
                       __HIP_MEMORY_SCOPE_AGENT);
}

// DPP butterfly add: x + perm(x). Valid for reduction levels where the
// permutation crosses the current group boundary (see call sites).
template <int CTRL>
static __device__ __forceinline__ float dpp_add(float x) {
    int v = __builtin_amdgcn_update_dpp(0, __builtin_bit_cast(int, x), CTRL, 0xF,
                                        0xF, true);
    return x + __builtin_bit_cast(float, v);
}
#define DPP_XOR1  0xB1   // quad_perm [1,0,3,2]
#define DPP_XOR2  0x4E   // quad_perm [2,3,0,1]
#define DPP_XOR4  0x141  // row_half_mirror (valid: groups of 4 uniform)
#define DPP_XOR8  0x128  // row_ror:8 (exact lane s <-> s+8 within row16)

// ---------------- f32 -> f16 convert ----------------
__global__ __launch_bounds__(256) void cvt_f32_f16(const float* __restrict__ in,
                                                   _Float16* __restrict__ out, int n) {
    int i = (blockIdx.x * 256 + threadIdx.x) * 4;
    if (i < n) {
        float4 v = *(const float4*)(in + i);
        out[i + 0] = (_Float16)v.x;
        out[i + 1] = (_Float16)v.y;
        out[i + 2] = (_Float16)v.z;
        out[i + 3] = (_Float16)v.w;
    }
}

// ---------------- init words (zero => {h=0, tag=0} == "h_0 valid") ----------------
__global__ __launch_bounds__(256) void init_state(unsigned long long* __restrict__ words) {
    int i = blockIdx.x * 256 + threadIdx.x;
    if (i < 4096) words[i] = 0ull;  // words[2][256][8] (each block: own 64-B line)
}

// ---------------- x_proj GEMM: C = A @ B^T, epilogue scattered into xp2 ----------
// xp2 layout: xp2[t][b*32 + g*8 + r] where r = gate*2 + (elem&1), g = (elem>>1)&3,
// b = elem>>3  (elem = col & 2047, gate = col >> 11). One 64-B line per block-step.
__global__ __launch_bounds__(256) void gemm_xproj(const _Float16* __restrict__ A,  // [SEQ][ISZ]
                                                  const _Float16* __restrict__ B,  // [G4H][ISZ]
                                                  _Float16* __restrict__ C) {      // [SEQ][G4H] permuted
    __shared__ _Float16 As[128 * 40];
    __shared__ _Float16 Bs[128 * 40];
    const int tid = threadIdx.x;
    const int bm = blockIdx.y, bn = blockIdx.x;
    const int wave = tid >> 6, lane = tid & 63;
    const int wr = wave >> 1, wc = wave & 1;
    const int l15 = lane & 15, lq = lane >> 4;

    float4_t acc[4][4];
#pragma unroll
    for (int im = 0; im < 4; im++)
#pragma unroll
        for (int in = 0; in < 4; in++)
#pragma unroll
            for (int r = 0; r < 4; r++) acc[im][in][r] = 0.f;

    for (int kt = 0; kt < ISZ; kt += 32) {
        __syncthreads();
#pragma unroll
        for (int ld = 0; ld < 2; ld++) {
            int c = tid + ld * 256;
            int r = c >> 2, ko = (c & 3) * 8;
            uint4 av = *(const uint4*)(A + (size_t)(bm * 128 + r) * ISZ + kt + ko);
            *(uint4*)(As + r * 40 + ko) = av;
            uint4 bv = *(const uint4*)(B + (size_t)(bn * 128 + r) * ISZ + kt + ko);
            *(uint4*)(Bs + r * 40 + ko) = bv;
        }
        __syncthreads();
        half8_t af[4], bf[4];
#pragma unroll
        for (int im = 0; im < 4; im++)
            af[im] = *(half8_t*)(As + (wr * 64 + im * 16 + l15) * 40 + lq * 8);
#pragma unroll
        for (int in = 0; in < 4; in++)
            bf[in] = *(half8_t*)(Bs + (wc * 64 + in * 16 + l15) * 40 + lq * 8);
#pragma unroll
        for (int im = 0; im < 4; im++)
#pragma unroll
            for (int in = 0; in < 4; in++)
                acc[im][in] = __builtin_amdgcn_mfma_f32_16x16x32_f16(af[im], bf[in], acc[im][in], 0, 0, 0);
    }
#pragma unroll
    for (int im = 0; im < 4; im++) {
        int mg = bm * 128 + wr * 64 + im * 16 + lq * 4;
#pragma unroll
        for (int in = 0; in < 4; in++) {
            int ng = bn * 128 + wc * 64 + in * 16 + l15;
            int gate = ng >> 11;
            int e = ng & 2047;
            int col2 = (e >> 3) * 32 + ((e >> 1) & 3) * 8 + gate * 2 + (e & 1);
#pragma unroll
            for (int r = 0; r < 4; r++)
                C[(size_t)(mg + r) * G4H + col2] = (_Float16)acc[im][in][r];
        }
    }
}

// ---------------- persistent LSTM recurrence ----------------
// Block b owns h[8b..8b+8). Wave g owns all 4 gates of elements {2g, 2g+1}
// (row r: gate=r>>1, elem=2g+(r&1)); each wave publishes its own
// self-validating word {tag32 | h_e1 | h_e0} — one barrier per step.
// Poll rotation: wave g lane j polls block 64g+((j+b)&63).
// LDS: 64 units x 80 B (16 data dwords + 4 pad), b128 conflict-free.
__global__ __launch_bounds__(256, 1) void lstm_persist(
    const float* __restrict__ Whh,   // [G4H][HID] f32
    const float* __restrict__ b_ih, const float* __restrict__ b_hh,
    const _Float16* __restrict__ xp, // [SEQ][G4H] f16, permuted layout
    const float* __restrict__ fcw, const float* __restrict__ fcb,
    unsigned long long* __restrict__ words,  // [2][256][8]
    float* __restrict__ out) {
    const int b = blockIdx.x, tid = threadIdx.x;
    const int g = tid >> 6, lane = tid & 63;
    const int pblk = (g << 6) | ((lane + b) & 63);  // block this lane polls/stages

    __shared__ unsigned h_lds32[2][1280];  // parity x (64 units x 20 dwords)

    // --- prologue: weight slice into registers (f32 -> f16) ---
    half2_t w[8][16];
#pragma unroll
    for (int r = 0; r < 8; r++) {
        const float* wp =
            Whh + (size_t)((r >> 1) * HID + b * 8 + 2 * g + (r & 1)) * HID + lane * 32;
#pragma unroll
        for (int i = 0; i < 16; i++) {
            float2 f = *(const float2*)(wp + i * 2);
            half2_t h2;
            h2.x = (_Float16)f.x;
            h2.y = (_Float16)f.y;
            w[r][i] = h2;
        }
    }
    float bias_r = 0.f;
    if (lane < 8) {
        int row = ((lane >> 1) & 3) * HID + b * 8 + 2 * g + (lane & 1);
        bias_r = b_ih[row] + b_hh[row];
    }
    float c_reg = 0.f;  // cell state of elem 2g+(lane&1)

    const int s_dw = (pblk >> 2) * 20 + (pblk & 3) * 4;  // LDS stage dst (dwords)
    const int xpbase = b * 32 + g * 8;                   // + lane (lanes 0..7)

    for (int t = 0; t < SEQ; ++t) {
        const unsigned ut = (unsigned)t;
        const int par = t & 1;

        // x_proj prefetch: one 64-B line per block-step (permuted layout)
        float xpv = 0.f;
        if (lane < 8) xpv = (float)xp[(size_t)t * G4H + xpbase + lane];

        // poll own block's 4 self-validating words (32 B/lane)
        const unsigned long long* wp = words + (size_t)par * 2048 + pblk * 8;
        unsigned long long v0, v1, v2, v3;
        for (;;) {
            v0 = ld_u64(wp + 0);
            v1 = ld_u64(wp + 1);
            v2 = ld_u64(wp + 2);
            v3 = ld_u64(wp + 3);
            bool ok = ((unsigned)(v0 >> 32) >= ut) && ((unsigned)(v1 >> 32) >= ut) &&
                      ((unsigned)(v2 >> 32) >= ut) && ((unsigned)(v3 >> 32) >= ut);
            if (__all(ok)) break;
            __builtin_amdgcn_s_sleep(1);
        }

        // stage 8 halves of block pblk into parity LDS buffer (one b128)
        *(uint4*)&h_lds32[par][s_dw] =
            make_uint4((unsigned)v0, (unsigned)v1, (unsigned)v2, (unsigned)v3);
        __syncthreads();  // the ONLY barrier: h_t fully staged

        // read slice [lane*32, lane*32+32) as 4 x b128 (80-B units, conflict-free)
        union {
            uint4 q[4];
            half2_t h2[16];
        } hu;
        const uint4* hp4 = (const uint4*)((const char*)&h_lds32[par][0] + 80 * lane);
#pragma unroll
        for (int i = 0; i < 4; i++) hu.q[i] = hp4[i];

        // matvec: 8 rows x 32 cols per lane
        float acc[8];
#pragma unroll
        for (int r = 0; r < 8; r++) {
            float a = 0.f;
#pragma unroll
            for (int i = 0; i < 16; i++) a = DOT2(w[r][i], hu.h2[i], a);
            acc[r] = a;
        }
        // reduce: DPP xor1/2/4 on all 8 accs, select, DPP xor8, shfl 16/32
#pragma unroll
        for (int r = 0; r < 8; r++) {
            acc[r] = dpp_add<DPP_XOR1>(acc[r]);
            acc[r] = dpp_add<DPP_XOR2>(acc[r]);
            acc[r] = dpp_add<DPP_XOR4>(acc[r]);
        }
        float u;
        {
            int s = lane & 7;
            float u01 = (s & 1) ? acc[1] : acc[0];
            float u23 = (s & 1) ? acc[3] : acc[2];
            float u45 = (s & 1) ? acc[5] : acc[4];
            float u67 = (s & 1) ? acc[7] : acc[6];
            float ua = (s & 2) ? u23 : u01;
            float ub = (s & 2) ? u67 : u45;
            u = (s & 4) ? ub : ua;
        }
        u = dpp_add<DPP_XOR8>(u);
        u += __shfl_xor(u, 16, 64);
        u += __shfl_xor(u, 32, 64);
        u += bias_r + xpv;  // valid in lanes 0..7 (sources of the gate shfls)

        // gates: rows [i_e0,i_e1,f_e0,f_e1,g_e0,g_e1,o_e0,o_e1] in lanes 0..7
        {
            int base = lane & 1;
            float gi = __shfl(u, base + 0, 64);
            float gf = __shfl(u, base + 2, 64);
            float gg = __shfl(u, base + 4, 64);
            float go = __shfl(u, base + 6, 64);
            float si = RCP(1.f + __expf(-gi));
            float sf = RCP(1.f + __expf(-gf));
            float so = RCP(1.f + __expf(-go));
            float tg = 1.f - 2.f * RCP(1.f + __expf(2.f * gg));
            c_reg = sf * c_reg + si * tg;
            float tc = 1.f - 2.f * RCP(1.f + __expf(2.f * c_reg));
            float h = so * tc;
            _Float16 hf = (_Float16)h;
            unsigned pk = *(unsigned short*)&hf;
            unsigned pk1 = __shfl(pk, 1, 64);
            if (lane == 0) {
                unsigned lo = pk | (pk1 << 16);
                unsigned long long wword =
                    (unsigned long long)lo | ((unsigned long long)(ut + 1) << 32);
                st_u64(words + (size_t)((t + 1) & 1) * 2048 + b * 8 + g, wword);
            }
        }
        // parity-double-buffered LDS + B1 ordering make cross-step reuse race-free
    }

    // --- final fc on h_SEQ (parity 0) by block 0 ---
    if (b == 0) {
        const int par = SEQ & 1;
        const unsigned long long* wp = words + (size_t)par * 2048 + pblk * 8;
        unsigned long long v0, v1, v2, v3;
        for (;;) {
            v0 = ld_u64(wp + 0);
            v1 = ld_u64(wp + 1);
            v2 = ld_u64(wp + 2);
            v3 = ld_u64(wp + 3);
            bool ok = ((unsigned)(v0 >> 32) >= (unsigned)SEQ) &&
                      ((unsigned)(v1 >> 32) >= (unsigned)SEQ) &&
                      ((unsigned)(v2 >> 32) >= (unsigned)SEQ) &&
                      ((unsigned)(v3 >> 32) >= (unsigned)SEQ);
            if (__all(ok)) break;
            __builtin_amdgcn_s_sleep(1);
        }
        *(uint4*)&h_lds32[par][s_dw] =
            make_uint4((unsigned)v0, (unsigned)v1, (unsigned)v2, (unsigned)v3);
        __syncthreads();
        if (g == 0) {
            union {
                uint4 q[4];
                half2_t h2[16];
            } hu;
            const uint4* hp4 = (const uint4*)((const char*)&h_lds32[par][0] + 80 * lane);
#pragma unroll
            for (int i = 0; i < 4; i++) hu.q[i] = hp4[i];
            float s = 0.f;
            const float* fw = fcw + lane * 32;
#pragma unroll
            for (int i = 0; i < 16; i++)
                s += (float)hu.h2[i].x * fw[2 * i] + (float)hu.h2[i].y * fw[2 * i + 1];
#pragma unroll
            for (int off = 1; off < 64; off <<= 1) s += __shfl_xor(s, off, 64);
            if (lane == 0) out[0] = s + fcb[0];
        }
    }
}

// ---------------- launch ----------------
extern "C" void kernel_launch(void* const* d_in, const int* in_sizes, int n_in,
                              void* d_out, int out_size, void* d_ws, size_t ws_size,
                              hipStream_t stream) {
    const float* input = (const float*)d_in[0];  // [SEQ][ISZ]
    const float* W_ih = (const float*)d_in[1];   // [G4H][ISZ]
    const float* W_hh = (const float*)d_in[2];   // [G4H][HID]
    const float* b_ih = (const float*)d_in[3];
    const float* b_hh = (const float*)d_in[4];
    const float* fc_w = (const float*)d_in[5];
    const float* fc_b = (const float*)d_in[6];
    float* out = (float*)d_out;

    char* ws = (char*)d_ws;
    _Float16* xp16 = (_Float16*)ws;               // 134,217,728 B
    _Float16* A16 = (_Float16*)(ws + 134217728);  // 8 MB (dead after gemm)
    _Float16* B16 = (_Float16*)(ws + 142606336);  // 8 MB (dead after gemm)
    // words overlay the dead A16 region (init_state runs AFTER gemm):
    unsigned long long* words = (unsigned long long*)(ws + 134217728);  // 32,768 B

    cvt_f32_f16<<<(SEQ * ISZ) / 1024, 256, 0, stream>>>(input, A16, SEQ * ISZ);
    cvt_f32_f16<<<(G4H * ISZ) / 1024, 256, 0, stream>>>(W_ih, B16, G4H * ISZ);

    dim3 gg(G4H / 128, SEQ / 128);
    gemm_xproj<<<gg, 256, 0, stream>>>(A16, B16, xp16);

    init_state<<<16, 256, 0, stream>>>(words);  // after gemm: A16 region is dead

    lstm_persist<<<NB, 256, 0, stream>>>(W_hh, b_ih, b_hh, xp16, fc_w, fc_b,
                                         words, out);
}